// Round 9
// baseline (23.705 us; speedup 1.0000x reference)
//
#include <hip/hip_runtime.h>

#define POOL 7
#define SCALE 0.0625f
#define HW 10000      // 100*100 plane elements
#define NROI 512
#define NCH 245
#define SSTRIDE 32    // c-stride between a block's planes
#define MAXPL 8

typedef const __attribute__((address_space(1))) void* gas_ptr;
typedef __attribute__((address_space(3))) void* las_ptr;

// 256 persistent blocks (1/CU), 512 threads = 512 rois of batch b = bid&7
// (XCD write-merge kept). Block (b,s) processes planes c = s + 32*t,
// t in [0,np), np = 8 (s<21) or 7. Triple-buffered LDS, prefetch depth 2:
//   iter t: stage(t+2) -> wait vmcnt(10|5|0) -> barrier -> gather -> barrier
// Results accumulate in registers; ALL out-stores after the loop, so the
// vmcnt queue holds ONLY global_load_lds ops and the counted ladder is exact
// (round-8's in-loop store polluted the count and re-serialized the stream).
// Every wave issues exactly 5 DMAs per stage; in-order retirement makes
// vmcnt(5*ahead) == "plane t fully in LDS".
__global__ __launch_bounds__(512) void psroi_kernel(
    const float* __restrict__ x, const float* __restrict__ boxes,
    float* __restrict__ out)
{
    __shared__ float plane[3][HW + 4];
    const int H = 100, W = 100;

    int bid = blockIdx.x;        // 256 blocks
    int b = bid & 7;             // batch == target XCD
    int s = bid >> 3;            // 0..31
    int np = (s < 21) ? 8 : 7;   // c = s + 32*t <= 244

    int n = threadIdx.x;              // roi within batch
    int r = b * NROI + n;             // global roi id
    int lane = threadIdx.x & 63;
    int wave = threadIdx.x >> 6;
    const float* xb = x + (size_t)b * NCH * HW;

    auto stage = [&](int buf, int c) {
        const float4* src4 = (const float4*)(xb + (size_t)c * HW);
        #pragma unroll
        for (int i = 0; i < 5; ++i) {
            int chunk_base = i * 512 + wave * 64;   // float4 units
            int chunk = chunk_base + lane;
            if (chunk < HW / 4) {
                __builtin_amdgcn_global_load_lds(
                    (gas_ptr)(src4 + chunk),
                    (las_ptr)((char*)&plane[buf][0] + (size_t)chunk_base * 16),
                    16, 0, 0);
            }
        }
    };

    // ---- prologue ----
    float4 bx = *(const float4*)(boxes + (size_t)r * 4);
    stage(0, s);
    stage(1, s + SSTRIDE);
    if (threadIdx.x < 12)
        plane[threadIdx.x >> 2][HW + (threadIdx.x & 3)] = 0.f;

    float sw = bx.x * SCALE - 0.5f;
    float sh = bx.y * SCALE - 0.5f;
    float bin_h = (bx.w * SCALE - 0.5f - sh) / (float)POOL;
    float bin_w = (bx.z * SCALE - 0.5f - sw) / (float)POOL;

    float res[MAXPL];

    #pragma unroll
    for (int t = 0; t < MAXPL; ++t) {
        if (t >= np) break;               // block-uniform: barriers stay legal
        if (t + 2 < np) stage((t + 2) % 3, s + SSTRIDE * (t + 2));

        int c = s + SSTRIDE * t;
        int ph = (c / POOL) % POOL;
        int pw = c % POOL;
        float fy0 = sh + (float)ph * bin_h;
        float fx0 = sw + (float)pw * bin_w;

        int   rowa[2], rstep[2];
        float wyh[2], wyl[2];
        #pragma unroll
        for (int iy = 0; iy < 2; ++iy) {
            float y  = fy0 + ((float)iy + 0.5f) * bin_h * 0.5f;
            float vy = (y >= -1.0f && y <= (float)H) ? 1.0f : 0.0f;
            float yc = fminf(fmaxf(y, 0.0f), (float)(H - 1));
            int   yl = (int)floorf(yc);
            float ly = yc - (float)yl;
            wyl[iy] = ly * vy;
            wyh[iy] = (1.0f - ly) * vy;
            rowa[iy]  = yl * W;
            rstep[iy] = (yl < H - 1) ? W : 0;
        }
        int   colx[2];
        float wxh[2], wxl[2];
        #pragma unroll
        for (int ix = 0; ix < 2; ++ix) {
            float xf = fx0 + ((float)ix + 0.5f) * bin_w * 0.5f;
            float vx = (xf >= -1.0f && xf <= (float)W) ? 1.0f : 0.0f;
            float xc = fminf(fmaxf(xf, 0.0f), (float)(W - 1));
            int   xl = (int)floorf(xc);
            float lx = xc - (float)xl;   // == 0 exactly when xl == W-1
            wxl[ix] = lx * vx;
            wxh[ix] = (1.0f - lx) * vx;
            colx[ix] = xl;
        }

        // wait for THIS plane only; up to 2 planes stay in flight
        int ahead = np - 1 - t; if (ahead > 2) ahead = 2;
        if (ahead == 2)
            asm volatile("s_waitcnt vmcnt(10) lgkmcnt(0)" ::: "memory");
        else if (ahead == 1)
            asm volatile("s_waitcnt vmcnt(5) lgkmcnt(0)" ::: "memory");
        else
            asm volatile("s_waitcnt vmcnt(0) lgkmcnt(0)" ::: "memory");
        __builtin_amdgcn_sched_barrier(0);
        __builtin_amdgcn_s_barrier();

        const float* pl = &plane[t % 3][0];
        float sum = 0.f;
        #pragma unroll
        for (int iy = 0; iy < 2; ++iy) {
            #pragma unroll
            for (int ix = 0; ix < 2; ++ix) {
                int a0 = rowa[iy] + colx[ix];
                int a1 = a0 + rstep[iy];
                float v11 = pl[a0];
                float v12 = pl[a0 + 1];
                float v21 = pl[a1];
                float v22 = pl[a1 + 1];
                float top = wxh[ix] * v11 + wxl[ix] * v12;
                float bot = wxh[ix] * v21 + wxl[ix] * v22;
                sum = fmaf(wyh[iy], top, sum);
                sum = fmaf(wyl[iy], bot, sum);
            }
        }
        res[t] = sum * 0.25f;

        __builtin_amdgcn_s_barrier();   // buffer reuse guard
    }

    // ---- epilogue: all stores (merge in XCD-local L2) ----
    float* outr = out + (size_t)r * NCH + s;
    #pragma unroll
    for (int t = 0; t < MAXPL; ++t) {
        if (t >= np) break;
        outr[SSTRIDE * t] = res[t];
    }
}

extern "C" void kernel_launch(void* const* d_in, const int* in_sizes, int n_in,
                              void* d_out, int out_size, void* d_ws, size_t ws_size,
                              hipStream_t stream) {
    const float* x     = (const float*)d_in[0];
    const float* boxes = (const float*)d_in[1];
    float* out = (float*)d_out;

    (void)in_sizes; (void)n_in; (void)out_size; (void)d_ws; (void)ws_size;

    hipLaunchKernelGGL(psroi_kernel, dim3(256), dim3(512), 0, stream,
                       x, boxes, out);
}

// Round 10
// 21.471 us; speedup vs baseline: 1.1040x; 1.1040x over previous
//
#include <hip/hip_runtime.h>

#define POOL 7
#define SCALE 0.0625f
#define HW 10000      // 100*100 plane elements
#define NROI 512
#define NCH 245
#define JJ 64         // c-stride between a block's planes
#define MAXPL 4

typedef const __attribute__((address_space(1))) void* gas_ptr;
typedef __attribute__((address_space(3))) void* las_ptr;

// 512 blocks (2/CU, 16 waves/CU), 512 threads = 512 rois of batch b = bid&7
// (XCD write-merge). Block (b,j) processes planes c = j + 64*t, np = 4 (j<53)
// else 3. Double-buffered LDS (80KB), prefetch depth 1:
//   iter t: stage(t+1) -> geometry -> s_waitcnt vmcnt(5) -> barrier
//           -> gather -> barrier
// Results held in registers; ALL out-stores in the epilogue, so the vmcnt
// queue holds ONLY global_load_lds ops. (Round 8 had the per-iter store in
// the queue: vmcnt(5) then forced retiring the store + one chunk of plane
// t+2, adding a full HBM latency to every iteration. This fixes that.)
// Every wave issues exactly 5 DMAs per stage; in-order retirement makes
// vmcnt(5) == "previous plane fully in LDS, prefetch still in flight".
__global__ __launch_bounds__(512) void psroi_kernel(
    const float* __restrict__ x, const float* __restrict__ boxes,
    float* __restrict__ out)
{
    __shared__ float plane[2][HW + 4];
    const int H = 100, W = 100;

    int bid = blockIdx.x;        // 512 blocks
    int b = bid & 7;             // batch == target XCD
    int j = bid >> 3;            // 0..63
    int np = (j < 53) ? 4 : 3;   // c = j + 64*t <= 244

    int n = threadIdx.x;              // roi within batch
    int r = b * NROI + n;             // global roi id
    int lane = threadIdx.x & 63;
    int wave = threadIdx.x >> 6;
    const float* xb = x + (size_t)b * NCH * HW;

    auto stage = [&](int buf, int c) {
        const float4* src4 = (const float4*)(xb + (size_t)c * HW);
        #pragma unroll
        for (int i = 0; i < 5; ++i) {
            int chunk_base = i * 512 + wave * 64;   // float4 units
            int chunk = chunk_base + lane;
            if (chunk < HW / 4) {
                __builtin_amdgcn_global_load_lds(
                    (gas_ptr)(src4 + chunk),
                    (las_ptr)((char*)&plane[buf][0] + (size_t)chunk_base * 16),
                    16, 0, 0);
            }
        }
    };

    // ---- prologue ----
    float4 bx = *(const float4*)(boxes + (size_t)r * 4);
    stage(0, j);
    if (threadIdx.x < 8)
        plane[threadIdx.x >> 2][HW + (threadIdx.x & 3)] = 0.f;

    float sw = bx.x * SCALE - 0.5f;
    float sh = bx.y * SCALE - 0.5f;
    float bin_h = (bx.w * SCALE - 0.5f - sh) / (float)POOL;
    float bin_w = (bx.z * SCALE - 0.5f - sw) / (float)POOL;

    __syncthreads();   // drains prologue vmcnt/lgkmcnt; outstanding = 0

    float res[MAXPL];

    #pragma unroll
    for (int t = 0; t < MAXPL; ++t) {
        if (t >= np) break;               // np is block-uniform
        bool pre = (t + 1 < np);
        if (pre) stage((t + 1) & 1, j + JJ * (t + 1));

        // per-plane geometry (VALU only; overlaps the in-flight DMA)
        int c = j + JJ * t;
        int ph = (c / POOL) % POOL;
        int pw = c % POOL;
        float fy0 = sh + (float)ph * bin_h;
        float fx0 = sw + (float)pw * bin_w;

        int   rowa[2], rstep[2];
        float wyh[2], wyl[2];
        #pragma unroll
        for (int iy = 0; iy < 2; ++iy) {
            float y  = fy0 + ((float)iy + 0.5f) * bin_h * 0.5f;
            float vy = (y >= -1.0f && y <= (float)H) ? 1.0f : 0.0f;
            float yc = fminf(fmaxf(y, 0.0f), (float)(H - 1));
            int   yl = (int)floorf(yc);
            float ly = yc - (float)yl;
            wyl[iy] = ly * vy;
            wyh[iy] = (1.0f - ly) * vy;
            rowa[iy]  = yl * W;
            rstep[iy] = (yl < H - 1) ? W : 0;
        }
        int   colx[2];
        float wxh[2], wxl[2];
        #pragma unroll
        for (int ix = 0; ix < 2; ++ix) {
            float xf = fx0 + ((float)ix + 0.5f) * bin_w * 0.5f;
            float vx = (xf >= -1.0f && xf <= (float)W) ? 1.0f : 0.0f;
            float xc = fminf(fmaxf(xf, 0.0f), (float)(W - 1));
            int   xl = (int)floorf(xc);
            float lx = xc - (float)xl;   // == 0 exactly when xl == W-1
            wxl[ix] = lx * vx;
            wxh[ix] = (1.0f - lx) * vx;
            colx[ix] = xl;
        }

        // wait for THIS plane only; prefetch (5 DMAs) stays in flight
        if (pre) asm volatile("s_waitcnt vmcnt(5)" ::: "memory");
        else     asm volatile("s_waitcnt vmcnt(0)" ::: "memory");
        __builtin_amdgcn_sched_barrier(0);
        __builtin_amdgcn_s_barrier();

        const float* pl = &plane[t & 1][0];
        float sum = 0.f;
        #pragma unroll
        for (int iy = 0; iy < 2; ++iy) {
            #pragma unroll
            for (int ix = 0; ix < 2; ++ix) {
                int a0 = rowa[iy] + colx[ix];
                int a1 = a0 + rstep[iy];
                float v11 = pl[a0];
                float v12 = pl[a0 + 1];
                float v21 = pl[a1];
                float v22 = pl[a1 + 1];
                float top = wxh[ix] * v11 + wxl[ix] * v12;
                float bot = wxh[ix] * v21 + wxl[ix] * v22;
                sum = fmaf(wyh[iy], top, sum);
                sum = fmaf(wyl[iy], bot, sum);
            }
        }
        res[t] = sum * 0.25f;

        __builtin_amdgcn_s_barrier();   // buffer reuse guard
    }

    // ---- epilogue: all stores (merge in XCD-local L2) ----
    float* outr = out + (size_t)r * NCH + j;
    #pragma unroll
    for (int t = 0; t < MAXPL; ++t) {
        if (t >= np) break;
        outr[JJ * t] = res[t];
    }
}

extern "C" void kernel_launch(void* const* d_in, const int* in_sizes, int n_in,
                              void* d_out, int out_size, void* d_ws, size_t ws_size,
                              hipStream_t stream) {
    const float* x     = (const float*)d_in[0];
    const float* boxes = (const float*)d_in[1];
    float* out = (float*)d_out;

    (void)in_sizes; (void)n_in; (void)out_size; (void)d_ws; (void)ws_size;

    hipLaunchKernelGGL(psroi_kernel, dim3(512), dim3(512), 0, stream,
                       x, boxes, out);
}

// Round 11
// 20.212 us; speedup vs baseline: 1.1728x; 1.0623x over previous
//
#include <hip/hip_runtime.h>

#define POOL 7
#define SCALE 0.0625f
#define HW 10000       // 100*100 plane elements
#define PLSZ 10004     // padded plane floats (pad 4, zeroed)
#define NROI 512
#define NCH 245

typedef const __attribute__((address_space(1))) void* gas_ptr;
typedef __attribute__((address_space(3))) void* las_ptr;

// Round 11: r7's winning one-shot structure (TLP > explicit pipelines, per
// r8/r9/r10), with per-block fixed costs halved: 1024 threads, 2 planes per
// block. Thread = (plane half g = tid>>9, roi n = tid&511). Each 8-wave half
// stages its own plane (5 DMAs/lane, global_load_lds w=16, linear dest),
// one __syncthreads, then gather+bilinear+direct store.
// 80KB LDS, 16 waves -> 2 blocks/CU = 32 waves/CU (same TLP as r7's 4x8).
// bid&7 = b keeps the XCD write-merge: all stores of batch b land in XCD b's
// L2; each 64B out line written back once, fully populated.
// Bilinear taps are paired (xl, xl+1): lx==0 exactly when xl==W-1; pad zeroed.
__global__ __launch_bounds__(1024) void psroi_kernel(
    const float* __restrict__ x, const float* __restrict__ boxes,
    float* __restrict__ out)
{
    __shared__ float plane[2][PLSZ];
    const int H = 100, W = 100;

    int bid = blockIdx.x;        // 8 * 123 blocks
    int b = bid & 7;             // batch == target XCD
    int k = bid >> 3;            // 0..122 -> planes c0, c0+1
    int c0 = 2 * k;

    int g = threadIdx.x >> 9;    // plane half 0/1 (wave-uniform)
    int n = threadIdx.x & 511;   // roi within batch
    int c = c0 + g;              // this thread's channel
    bool act = (c < NCH);        // only k==122,g==1 inactive

    int r = b * NROI + n;        // global roi id
    int lane = threadIdx.x & 63;
    int wave = (threadIdx.x >> 6) & 7;   // wave within half
    const float* xb = x + (size_t)b * NCH * HW;

    // ---- boxes load first ----
    float4 bx = *(const float4*)(boxes + (size_t)r * 4);

    // ---- each half stages its own plane: 2500 x 16B DMAs ----
    if (act) {
        const float4* src4 = (const float4*)(xb + (size_t)c * HW);
        char* lds = (char*)&plane[g][0];
        #pragma unroll
        for (int i = 0; i < 5; ++i) {
            int chunk_base = i * 512 + wave * 64;   // float4 units
            int chunk = chunk_base + lane;
            if (chunk < HW / 4) {
                __builtin_amdgcn_global_load_lds(
                    (gas_ptr)(src4 + chunk),
                    (las_ptr)(lds + (size_t)chunk_base * 16),
                    16, 0, 0);
            }
        }
    }
    if (threadIdx.x < 8)
        plane[threadIdx.x >> 2][HW + (threadIdx.x & 3)] = 0.f;

    // ---- per-roi geometry (overlaps the DMA; needs only boxes) ----
    float sw = bx.x * SCALE - 0.5f;
    float sh = bx.y * SCALE - 0.5f;
    float bin_h = (bx.w * SCALE - 0.5f - sh) / (float)POOL;
    float bin_w = (bx.z * SCALE - 0.5f - sw) / (float)POOL;

    int ph = (c / POOL) % POOL;
    int pw = c % POOL;
    float fy0 = sh + (float)ph * bin_h;
    float fx0 = sw + (float)pw * bin_w;

    int   rowa[2], rstep[2];
    float wyh[2], wyl[2];
    #pragma unroll
    for (int iy = 0; iy < 2; ++iy) {
        float y  = fy0 + ((float)iy + 0.5f) * bin_h * 0.5f;
        float vy = (y >= -1.0f && y <= (float)H) ? 1.0f : 0.0f;
        float yc = fminf(fmaxf(y, 0.0f), (float)(H - 1));
        int   yl = (int)floorf(yc);
        float ly = yc - (float)yl;
        wyl[iy] = ly * vy;
        wyh[iy] = (1.0f - ly) * vy;
        rowa[iy]  = yl * W;
        rstep[iy] = (yl < H - 1) ? W : 0;
    }
    int   colx[2];
    float wxh[2], wxl[2];
    #pragma unroll
    for (int ix = 0; ix < 2; ++ix) {
        float xf = fx0 + ((float)ix + 0.5f) * bin_w * 0.5f;
        float vx = (xf >= -1.0f && xf <= (float)W) ? 1.0f : 0.0f;
        float xc = fminf(fmaxf(xf, 0.0f), (float)(W - 1));
        int   xl = (int)floorf(xc);
        float lx = xc - (float)xl;   // == 0 exactly when xl == W-1
        wxl[ix] = lx * vx;
        wxh[ix] = (1.0f - lx) * vx;
        colx[ix] = xl;
    }

    __syncthreads();   // drains vmcnt; both planes resident

    if (!act) return;

    // ---- gather + bilinear ----
    const float* pl = &plane[g][0];
    float sum = 0.f;
    #pragma unroll
    for (int iy = 0; iy < 2; ++iy) {
        #pragma unroll
        for (int ix = 0; ix < 2; ++ix) {
            int a0 = rowa[iy] + colx[ix];
            int a1 = a0 + rstep[iy];
            float v11 = pl[a0];
            float v12 = pl[a0 + 1];
            float v21 = pl[a1];
            float v22 = pl[a1 + 1];
            float top = wxh[ix] * v11 + wxl[ix] * v12;
            float bot = wxh[ix] * v21 + wxl[ix] * v22;
            sum = fmaf(wyh[iy], top, sum);
            sum = fmaf(wyl[iy], bot, sum);
        }
    }
    out[(size_t)r * NCH + c] = sum * 0.25f;   // merges in XCD-local L2
}

extern "C" void kernel_launch(void* const* d_in, const int* in_sizes, int n_in,
                              void* d_out, int out_size, void* d_ws, size_t ws_size,
                              hipStream_t stream) {
    const float* x     = (const float*)d_in[0];
    const float* boxes = (const float*)d_in[1];
    float* out = (float*)d_out;

    (void)in_sizes; (void)n_in; (void)out_size; (void)d_ws; (void)ws_size;

    hipLaunchKernelGGL(psroi_kernel, dim3(8 * 123), dim3(1024), 0, stream,
                       x, boxes, out);
}

// Round 12
// 19.209 us; speedup vs baseline: 1.2341x; 1.0522x over previous
//
#include <hip/hip_runtime.h>

#define POOL 7
#define SCALE 0.0625f
#define HW 10000      // 100*100 plane elements
#define NROI 512
#define NCH 245

typedef const __attribute__((address_space(1))) void* gas_ptr;
typedef __attribute__((address_space(3))) void* las_ptr;

// Round 12: r7's one-shot structure (best: 19.2us), ILP variant.
// One block = one (b,c) plane, 256 threads, 2 rois per thread (n, n+256):
// doubles independent gather/geometry chains per wave (latency hiding via
// ILP instead of pure TLP). 40KB LDS -> 4 blocks/CU. bid&7 = b keeps the
// XCD write-merge (stores of batch b land in XCD b's L2, lines written back
// once, full). Stage = 10 global_load_lds (w=16) per lane, linear dest.
// Bilinear taps paired (xl, xl+1): lx==0 exactly when xl==W-1; pad zeroed.
__global__ __launch_bounds__(256) void psroi_kernel(
    const float* __restrict__ x, const float* __restrict__ boxes,
    float* __restrict__ out)
{
    __shared__ float plane[HW + 4];
    const int H = 100, W = 100;

    int bid = blockIdx.x;
    int b = bid & 7;             // batch == target XCD
    int c = bid >> 3;            // channel 0..244
    int ph = (c / POOL) % POOL;
    int pw = c % POOL;

    int tid  = threadIdx.x;
    int lane = tid & 63;
    int wave = tid >> 6;         // 0..3

    // ---- boxes loads first (retire before the 10 stage DMAs) ----
    int r0 = b * NROI + tid;     // roi n = tid
    int r1 = r0 + 256;           // roi n+256
    float4 bx0 = *(const float4*)(boxes + (size_t)r0 * 4);
    float4 bx1 = *(const float4*)(boxes + (size_t)r1 * 4);

    // ---- stage plane: 2500 x 16B DMAs, 10 per lane ----
    const float4* src4 = (const float4*)(x + ((size_t)b * NCH + c) * HW);
    #pragma unroll
    for (int i = 0; i < 10; ++i) {
        int chunk_base = i * 256 + wave * 64;   // float4 units, wave-uniform
        int chunk = chunk_base + lane;
        if (chunk < HW / 4) {
            __builtin_amdgcn_global_load_lds(
                (gas_ptr)(src4 + chunk),
                (las_ptr)((char*)plane + (size_t)chunk_base * 16),
                16, 0, 0);
        }
    }
    if (tid < 4) plane[HW + tid] = 0.f;

    // ---- geometry for both rois (VALU only; overlaps the DMA) ----
    float wyh[2][2], wyl[2][2], wxh[2][2], wxl[2][2];
    int   rowa[2][2], rstep[2][2], colx[2][2];
    #pragma unroll
    for (int q = 0; q < 2; ++q) {
        float4 bx = (q == 0) ? bx0 : bx1;
        float sw = bx.x * SCALE - 0.5f;
        float sh = bx.y * SCALE - 0.5f;
        float bin_h = (bx.w * SCALE - 0.5f - sh) / (float)POOL;
        float bin_w = (bx.z * SCALE - 0.5f - sw) / (float)POOL;
        float fy0 = sh + (float)ph * bin_h;
        float fx0 = sw + (float)pw * bin_w;
        #pragma unroll
        for (int iy = 0; iy < 2; ++iy) {
            float y  = fy0 + ((float)iy + 0.5f) * bin_h * 0.5f;
            float vy = (y >= -1.0f && y <= (float)H) ? 1.0f : 0.0f;
            float yc = fminf(fmaxf(y, 0.0f), (float)(H - 1));
            int   yl = (int)floorf(yc);
            float ly = yc - (float)yl;
            wyl[q][iy] = ly * vy;
            wyh[q][iy] = (1.0f - ly) * vy;
            rowa[q][iy]  = yl * W;
            rstep[q][iy] = (yl < H - 1) ? W : 0;
        }
        #pragma unroll
        for (int ix = 0; ix < 2; ++ix) {
            float xf = fx0 + ((float)ix + 0.5f) * bin_w * 0.5f;
            float vx = (xf >= -1.0f && xf <= (float)W) ? 1.0f : 0.0f;
            float xc = fminf(fmaxf(xf, 0.0f), (float)(W - 1));
            int   xl = (int)floorf(xc);
            float lx = xc - (float)xl;   // == 0 exactly when xl == W-1
            wxl[q][ix] = lx * vx;
            wxh[q][ix] = (1.0f - lx) * vx;
            colx[q][ix] = xl;
        }
    }

    __syncthreads();   // drains vmcnt; plane resident

    // ---- two independent gather+bilinear chains ----
    float res[2];
    #pragma unroll
    for (int q = 0; q < 2; ++q) {
        float sum = 0.f;
        #pragma unroll
        for (int iy = 0; iy < 2; ++iy) {
            #pragma unroll
            for (int ix = 0; ix < 2; ++ix) {
                int a0 = rowa[q][iy] + colx[q][ix];
                int a1 = a0 + rstep[q][iy];
                float v11 = plane[a0];
                float v12 = plane[a0 + 1];
                float v21 = plane[a1];
                float v22 = plane[a1 + 1];
                float top = wxh[q][ix] * v11 + wxl[q][ix] * v12;
                float bot = wxh[q][ix] * v21 + wxl[q][ix] * v22;
                sum = fmaf(wyh[q][iy], top, sum);
                sum = fmaf(wyl[q][iy], bot, sum);
            }
        }
        res[q] = sum * 0.25f;
    }
    out[(size_t)r0 * NCH + c] = res[0];   // merges in XCD-local L2
    out[(size_t)r1 * NCH + c] = res[1];
}

extern "C" void kernel_launch(void* const* d_in, const int* in_sizes, int n_in,
                              void* d_out, int out_size, void* d_ws, size_t ws_size,
                              hipStream_t stream) {
    const float* x     = (const float*)d_in[0];
    const float* boxes = (const float*)d_in[1];
    float* out = (float*)d_out;

    (void)in_sizes; (void)n_in; (void)out_size; (void)d_ws; (void)ws_size;

    hipLaunchKernelGGL(psroi_kernel, dim3(NCH * 8), dim3(256), 0, stream,
                       x, boxes, out);
}